// Round 9
// baseline (1440.056 us; speedup 1.0000x reference)
//
#include <hip/hip_runtime.h>

#define AA 60
#define HH 96
#define WW 96
#define DD 96
#define HWP (HH * WW)   // 9216
#define ADP (AA * DD)   // 5760
#define NITER 10
#define MATEL (60 * 96 * 9216)   // 53,084,160 elements per system matrix

typedef unsigned short ushort8 __attribute__((ext_vector_type(8)));
typedef float float4v __attribute__((ext_vector_type(4)));

__device__ inline float b2f(unsigned short u) {
    return __uint_as_float(((unsigned)u) << 16);
}
__device__ inline unsigned short f2b(float f) {
    unsigned u = __float_as_uint(f);
    u += 0x7FFFu + ((u >> 16) & 1u);
    return (unsigned short)(u >> 16);
}

// ---- f32 -> bf16 straight convert (one matrix half per dispatch) ----
__global__ __launch_bounds__(256) void cvtA_kernel(const float* __restrict__ src,
                                                   ushort8* __restrict__ dst,
                                                   int base) {
    int i = base + blockIdx.x * 256 + threadIdx.x;
    const float4v* s = reinterpret_cast<const float4v*>(src) + 2 * (size_t)i;
    float4v x = __builtin_nontemporal_load(s);
    float4v y = __builtin_nontemporal_load(s + 1);
    ushort8 o;
    o[0] = f2b(x[0]); o[1] = f2b(x[1]); o[2] = f2b(x[2]); o[3] = f2b(x[3]);
    o[4] = f2b(y[0]); o[5] = f2b(y[1]); o[6] = f2b(y[2]); o[7] = f2b(y[3]);
    dst[i] = o;
}

// xd[3][5760]: ch0=dual, ch1=evalop1, ch2=g ; xp[6][9216]: ch0..4=p2d, ch5=evalop2
__global__ __launch_bounds__(256) void init_kernel(const float* __restrict__ dual,
                            const float* __restrict__ g,
                            const float* __restrict__ primal,
                            float* __restrict__ xd, float* __restrict__ xp,
                            float* __restrict__ imgf, float* __restrict__ xp5) {
    int i = blockIdx.x * 256 + threadIdx.x;
    if (i < ADP) { xd[i] = dual[i]; xd[2 * ADP + i] = g[i]; }
    if (i < 5 * HWP) xp[i] = primal[i];
    if (i < HWP) {
        imgf[(i % WW) * HH + i / WW] = primal[HWP + i];
        xp5[i] = 0.f;
    }
}

// prod[row] = dot(norm_bf16[row,:9216], imgf); one wave per ROW-PAIR
// (imgf loads shared across the two rows -> half the L1/L2 broadcast traffic)
__global__ __launch_bounds__(256) void einsum1_kernel(const unsigned short* __restrict__ norm,
                               const float* __restrict__ imgf,
                               float* __restrict__ out) {
    int rp   = blockIdx.x * 4 + (threadIdx.x >> 6);   // 0..2879
    int lane = threadIdx.x & 63;
    const unsigned short* r0 = norm + (size_t)(2 * rp) * HWP;
    const unsigned short* r1 = r0 + HWP;
    float s0 = 0.f, s1 = 0.f;
    for (int k = 0; k < HWP / 512; ++k) {   // 18 iters
        int n = 8 * lane + 512 * k;
        ushort8 a8 = *reinterpret_cast<const ushort8*>(r0 + n);
        ushort8 b8 = *reinterpret_cast<const ushort8*>(r1 + n);
        float4 i0 = *reinterpret_cast<const float4*>(imgf + n);
        float4 i1 = *reinterpret_cast<const float4*>(imgf + n + 4);
        s0 += b2f(a8[0]) * i0.x + b2f(a8[1]) * i0.y + b2f(a8[2]) * i0.z + b2f(a8[3]) * i0.w
            + b2f(a8[4]) * i1.x + b2f(a8[5]) * i1.y + b2f(a8[6]) * i1.z + b2f(a8[7]) * i1.w;
        s1 += b2f(b8[0]) * i0.x + b2f(b8[1]) * i0.y + b2f(b8[2]) * i0.z + b2f(b8[3]) * i0.w
            + b2f(b8[4]) * i1.x + b2f(b8[5]) * i1.y + b2f(b8[6]) * i1.z + b2f(b8[7]) * i1.w;
    }
#pragma unroll
    for (int off = 32; off > 0; off >>= 1) {
        s0 += __shfl_down(s0, off);
        s1 += __shfl_down(s1, off);
    }
    if (lane == 0) { out[2 * rp] = s0; out[2 * rp + 1] = s1; }
}

// vec[v] = sum_{a,n} sysm_bf16[a,v,n]*dual[a,n]; fortran-transposed scatter
__global__ __launch_bounds__(256) void einsum2_kernel(const unsigned short* __restrict__ sysm,
                               const float* __restrict__ xd,
                               float* __restrict__ xp5) {
    __shared__ float sd[4 * DD];
    int t  = threadIdx.x;
    int a0 = (blockIdx.x % 15) * 4;
    int v  = (blockIdx.x / 15) * 256 + t;
    for (int j = t; j < 4 * DD; j += 256) sd[j] = xd[a0 * DD + j];
    __syncthreads();
    float s = 0.f;
    for (int ai = 0; ai < 4; ++ai) {
        const unsigned short* row = sysm + ((size_t)(a0 + ai) * HWP + v) * DD;
        const float* dl = sd + ai * DD;
#pragma unroll
        for (int jj = 0; jj < DD / 8; ++jj) {
            ushort8 m8 = *reinterpret_cast<const ushort8*>(row + 8 * jj);
            s += b2f(m8[0]) * dl[8 * jj]     + b2f(m8[1]) * dl[8 * jj + 1]
               + b2f(m8[2]) * dl[8 * jj + 2] + b2f(m8[3]) * dl[8 * jj + 3]
               + b2f(m8[4]) * dl[8 * jj + 4] + b2f(m8[5]) * dl[8 * jj + 5]
               + b2f(m8[6]) * dl[8 * jj + 6] + b2f(m8[7]) * dl[8 * jj + 7];
        }
    }
    atomicAdd(xp5 + (v % HH) * WW + (v / HH), s);
}

// 3x3 conv pad=1, PReLU. Grid: (hw/64, Cout/NOUT), block 64.
// ci-loop unrolled 4x for outstanding-load depth (latency-bound regime).
template <int CIN, int NOUT>
__global__ __launch_bounds__(64) void conv_mid(
        const float* __restrict__ in,
        const float* __restrict__ wgt,   // [Cout][CIN][3][3]
        const float* __restrict__ bias,
        const float* __restrict__ alpha,
        float* __restrict__ out,
        int Hc, int Wc) {
    int hw  = Hc * Wc;
    int pix = blockIdx.x * 64 + threadIdx.x;
    int y = pix / Wc, x = pix % Wc;
    int oc0 = blockIdx.y * NOUT;
    const float* wb = wgt + (size_t)oc0 * CIN * 9;
    float a = alpha[0];
    float acc[NOUT];
#pragma unroll
    for (int o = 0; o < NOUT; ++o) acc[o] = bias[oc0 + o];
#pragma unroll 4
    for (int ci = 0; ci < CIN; ++ci) {
        const float* ip = in + ci * hw;
#pragma unroll
        for (int ky = 0; ky < 3; ++ky) {
            int yy = y + ky - 1;
            bool yok = (unsigned)yy < (unsigned)Hc;
#pragma unroll
            for (int kx = 0; kx < 3; ++kx) {
                int xx = x + kx - 1;
                bool vok = yok && ((unsigned)xx < (unsigned)Wc);
                float v = ip[vok ? yy * Wc + xx : 0];
                v = vok ? v : 0.f;
#pragma unroll
                for (int o = 0; o < NOUT; ++o)
                    acc[o] += wb[(o * CIN + ci) * 9 + ky * 3 + kx] * v;
            }
        }
    }
#pragma unroll
    for (int o = 0; o < NOUT; ++o) {
        float r = acc[o];
        r = (r >= 0.f) ? r : a * r;
        out[(oc0 + o) * hw + pix] = r;
    }
}

// dual conv3 (32->1) + residual into xd ch0, split over ci-chunks of 4 (atomicAdd)
__global__ __launch_bounds__(64) void conv3d_last(const float* __restrict__ in,
        const float* __restrict__ wgt,   // [32][9]
        const float* __restrict__ bias,  // [1]
        float* __restrict__ xd) {
    int pix = blockIdx.x * 64 + threadIdx.x;   // 0..5759
    int y = pix / DD, x = pix % DD;
    int c0 = blockIdx.y * 4;
    float r = (blockIdx.y == 0) ? bias[0] : 0.f;
#pragma unroll
    for (int cc = 0; cc < 4; ++cc) {
        int ci = c0 + cc;
        const float* ip = in + ci * ADP;
#pragma unroll
        for (int ky = 0; ky < 3; ++ky) {
            int yy = y + ky - 1;
            bool yok = (unsigned)yy < (unsigned)AA;
#pragma unroll
            for (int kx = 0; kx < 3; ++kx) {
                int xx = x + kx - 1;
                bool vok = yok && ((unsigned)xx < (unsigned)DD);
                float v = ip[vok ? yy * DD + xx : 0];
                v = vok ? v : 0.f;
                r += wgt[ci * 9 + ky * 3 + kx] * v;
            }
        }
    }
    atomicAdd(xd + pix, r);
}

// primal conv3 (32->5) + residual into xp; fused: imgf for next iter (ch1),
// xp5 zero (ch2 block), final output write (ch0 block, last iter)
__global__ __launch_bounds__(64) void conv3p_last(const float* __restrict__ in,
        const float* __restrict__ wgt,   // [5][32][9]
        const float* __restrict__ bias,  // [5]
        float* __restrict__ xp, float* __restrict__ imgf,
        float* __restrict__ xp5, float* __restrict__ dout, int fin) {
    int pix = blockIdx.x * 64 + threadIdx.x;   // 0..9215
    int y = pix / WW, x = pix % WW;
    int oc = blockIdx.y;                       // 0..4
    const float* wb = wgt + (size_t)oc * 32 * 9;
    float r = bias[oc];
#pragma unroll 4
    for (int ci = 0; ci < 32; ++ci) {
        const float* ip = in + ci * HWP;
#pragma unroll
        for (int ky = 0; ky < 3; ++ky) {
            int yy = y + ky - 1;
            bool yok = (unsigned)yy < (unsigned)HH;
#pragma unroll
            for (int kx = 0; kx < 3; ++kx) {
                int xx = x + kx - 1;
                bool vok = yok && ((unsigned)xx < (unsigned)WW);
                float v = ip[vok ? yy * WW + xx : 0];
                v = vok ? v : 0.f;
                r += wb[ci * 9 + ky * 3 + kx] * v;
            }
        }
    }
    float nv = xp[oc * HWP + pix] + r;
    xp[oc * HWP + pix] = nv;
    if (oc == 1) imgf[x * HH + y] = nv;    // fortran flatten for next einsum1
    if (oc == 2) xp5[pix] = 0.f;           // clear evalop2 accumulator
    if (fin && oc == 0) dout[pix] = nv;    // final output
}

extern "C" void kernel_launch(void* const* d_in, const int* in_sizes, int n_in,
                              void* d_out, int out_size, void* d_ws, size_t ws_size,
                              hipStream_t stream) {
    const float* dual   = (const float*)d_in[0];
    const float* primal = (const float*)d_in[1];
    const float* g      = (const float*)d_in[2];
    const float* sysm   = (const float*)d_in[3];
    const float* norm   = (const float*)d_in[4];
    const float* dw1 = (const float*)d_in[5];
    const float* db1 = (const float*)d_in[6];
    const float* da1 = (const float*)d_in[7];
    const float* dw2 = (const float*)d_in[8];
    const float* db2 = (const float*)d_in[9];
    const float* da2 = (const float*)d_in[10];
    const float* dw3 = (const float*)d_in[11];
    const float* db3 = (const float*)d_in[12];
    const float* pw1 = (const float*)d_in[13];
    const float* pb1 = (const float*)d_in[14];
    const float* pa1 = (const float*)d_in[15];
    const float* pw2 = (const float*)d_in[16];
    const float* pb2 = (const float*)d_in[17];
    const float* pa2 = (const float*)d_in[18];
    const float* pw3 = (const float*)d_in[19];
    const float* pb3 = (const float*)d_in[20];

    unsigned short* normb = (unsigned short*)d_ws;     // MATEL bf16 [row][n]
    unsigned short* sysmb = normb + MATEL;             // MATEL bf16 [a][v][n]
    float* xd   = (float*)(sysmb + MATEL);             // 3*5760
    float* xp   = xd + 3 * ADP;                        // 6*9216
    float* imgf = xp + 6 * HWP;                        // 9216
    float* h1   = imgf + HWP;                          // 32*5760
    float* h2   = h1 + 32 * ADP;                       // 32*5760
    float* g1   = h2 + 32 * ADP;                       // 32*9216
    float* g2   = g1 + 32 * HWP;                       // 32*9216

    const int N8 = MATEL / 8;            // 6,635,520
    const int HN = N8 / 2;               // 3,317,760 (divisible by 256)
    cvtA_kernel<<<HN / 256, 256, 0, stream>>>(norm, (ushort8*)normb, 0);
    cvtA_kernel<<<HN / 256, 256, 0, stream>>>(norm, (ushort8*)normb, HN);
    cvtA_kernel<<<HN / 256, 256, 0, stream>>>(sysm, (ushort8*)sysmb, 0);
    cvtA_kernel<<<HN / 256, 256, 0, stream>>>(sysm, (ushort8*)sysmb, HN);
    init_kernel<<<(5 * HWP + 255) / 256, 256, 0, stream>>>(dual, g, primal, xd, xp, imgf, xp + 5 * HWP);

    for (int k = 0; k < NITER; ++k) {
        // ---- dual half ----
        einsum1_kernel<<<ADP / 8, 256, 0, stream>>>(normb, imgf, xd + ADP);
        conv_mid<3, 2><<<dim3(ADP / 64, 16), 64, 0, stream>>>(
            xd, dw1 + k * 32 * 3 * 9, db1 + k * 32, da1 + k, h1, AA, DD);
        conv_mid<32, 2><<<dim3(ADP / 64, 16), 64, 0, stream>>>(
            h1, dw2 + k * 32 * 32 * 9, db2 + k * 32, da2 + k, h2, AA, DD);
        conv3d_last<<<dim3(ADP / 64, 8), 64, 0, stream>>>(
            h2, dw3 + k * 32 * 9, db3 + k, xd);
        // ---- primal half ----
        einsum2_kernel<<<15 * 36, 256, 0, stream>>>(sysmb, xd, xp + 5 * HWP);
        conv_mid<6, 2><<<dim3(HWP / 64, 16), 64, 0, stream>>>(
            xp, pw1 + k * 32 * 6 * 9, pb1 + k * 32, pa1 + k, g1, HH, WW);
        conv_mid<32, 2><<<dim3(HWP / 64, 16), 64, 0, stream>>>(
            g1, pw2 + k * 32 * 32 * 9, pb2 + k * 32, pa2 + k, g2, HH, WW);
        conv3p_last<<<dim3(HWP / 64, 5), 64, 0, stream>>>(
            g2, pw3 + k * 5 * 32 * 9, pb3 + k * 5, xp, imgf, xp + 5 * HWP,
            (float*)d_out, k == NITER - 1 ? 1 : 0);
    }
}

// Round 10
// 1132.840 us; speedup vs baseline: 1.2712x; 1.2712x over previous
//
#include <hip/hip_runtime.h>

#define AA 60
#define HH 96
#define WW 96
#define DD 96
#define HWP (HH * WW)   // 9216
#define ADP (AA * DD)   // 5760
#define NITER 10
#define MATEL (60 * 96 * 9216)   // 53,084,160 elements per system matrix

typedef unsigned short ushort8 __attribute__((ext_vector_type(8)));
typedef float float4v __attribute__((ext_vector_type(4)));

__device__ inline float b2f(unsigned short u) {
    return __uint_as_float(((unsigned)u) << 16);
}
__device__ inline unsigned short f2b(float f) {
    unsigned u = __float_as_uint(f);
    u += 0x7FFFu + ((u >> 16) & 1u);
    return (unsigned short)(u >> 16);
}

// ---- f32 -> bf16 conversion of both system matrices (once per call) ----
__global__ __launch_bounds__(256) void cvt_kernel(const float* __restrict__ a,
                                                  const float* __restrict__ b,
                                                  ushort8* __restrict__ da,
                                                  ushort8* __restrict__ db, int n8) {
    int stride = gridDim.x * 256;
    for (int i = blockIdx.x * 256 + threadIdx.x; i < 2 * n8; i += stride) {
        const float* src; ushort8* dst; int j;
        if (i < n8) { src = a; dst = da; j = i; }
        else        { src = b; dst = db; j = i - n8; }
        const float4v* s = reinterpret_cast<const float4v*>(src) + 2 * (size_t)j;
        float4v x = __builtin_nontemporal_load(s);
        float4v y = __builtin_nontemporal_load(s + 1);
        ushort8 o;
        o[0] = f2b(x[0]); o[1] = f2b(x[1]); o[2] = f2b(x[2]); o[3] = f2b(x[3]);
        o[4] = f2b(y[0]); o[5] = f2b(y[1]); o[6] = f2b(y[2]); o[7] = f2b(y[3]);
        dst[j] = o;
    }
}

// xd[3][5760]: ch0=dual, ch1=evalop1, ch2=g ; xp[6][9216]: ch0..4=p2d, ch5=evalop2
__global__ __launch_bounds__(256) void init_kernel(const float* __restrict__ dual,
                            const float* __restrict__ g,
                            const float* __restrict__ primal,
                            float* __restrict__ xd, float* __restrict__ xp,
                            float* __restrict__ imgf, float* __restrict__ xp5) {
    int i = blockIdx.x * 256 + threadIdx.x;
    if (i < ADP) { xd[i] = dual[i]; xd[2 * ADP + i] = g[i]; }
    if (i < 5 * HWP) xp[i] = primal[i];
    if (i < HWP) {
        imgf[(i % WW) * HH + i / WW] = primal[HWP + i];
        xp5[i] = 0.f;
    }
}

// prod[row] = dot(norm_bf16[row,:9216], imgf); one wave per row
__global__ __launch_bounds__(256) void einsum1_kernel(const unsigned short* __restrict__ norm,
                               const float* __restrict__ imgf,
                               float* __restrict__ out) {
    int row  = blockIdx.x * 4 + (threadIdx.x >> 6);
    int lane = threadIdx.x & 63;
    const unsigned short* mr = norm + (size_t)row * HWP;
    float s = 0.f;
    for (int k = 0; k < HWP / 512; ++k) {   // 18 iters
        int n = 8 * lane + 512 * k;
        ushort8 m8 = *reinterpret_cast<const ushort8*>(mr + n);
        float4 i0 = *reinterpret_cast<const float4*>(imgf + n);
        float4 i1 = *reinterpret_cast<const float4*>(imgf + n + 4);
        s += b2f(m8[0]) * i0.x + b2f(m8[1]) * i0.y + b2f(m8[2]) * i0.z + b2f(m8[3]) * i0.w
           + b2f(m8[4]) * i1.x + b2f(m8[5]) * i1.y + b2f(m8[6]) * i1.z + b2f(m8[7]) * i1.w;
    }
#pragma unroll
    for (int off = 32; off > 0; off >>= 1) s += __shfl_down(s, off);
    if (lane == 0) out[row] = s;
}

// vec[v] = sum_{a,n} sysm_bf16[a,v,n]*dual[a,n]; fortran-transposed scatter
__global__ __launch_bounds__(256) void einsum2_kernel(const unsigned short* __restrict__ sysm,
                               const float* __restrict__ xd,
                               float* __restrict__ xp5) {
    __shared__ float sd[4 * DD];
    int t  = threadIdx.x;
    int a0 = (blockIdx.x % 15) * 4;
    int v  = (blockIdx.x / 15) * 256 + t;
    for (int j = t; j < 4 * DD; j += 256) sd[j] = xd[a0 * DD + j];
    __syncthreads();
    float s = 0.f;
    for (int ai = 0; ai < 4; ++ai) {
        const unsigned short* row = sysm + ((size_t)(a0 + ai) * HWP + v) * DD;
        const float* dl = sd + ai * DD;
#pragma unroll
        for (int jj = 0; jj < DD / 8; ++jj) {
            ushort8 m8 = *reinterpret_cast<const ushort8*>(row + 8 * jj);
            s += b2f(m8[0]) * dl[8 * jj]     + b2f(m8[1]) * dl[8 * jj + 1]
               + b2f(m8[2]) * dl[8 * jj + 2] + b2f(m8[3]) * dl[8 * jj + 3]
               + b2f(m8[4]) * dl[8 * jj + 4] + b2f(m8[5]) * dl[8 * jj + 5]
               + b2f(m8[6]) * dl[8 * jj + 6] + b2f(m8[7]) * dl[8 * jj + 7];
        }
    }
    atomicAdd(xp5 + (v % HH) * WW + (v / HH), s);
}

// 3x3 conv pad=1, PReLU. Grid: (hw/64, Cout/NOUT), block 64.
template <int CIN, int NOUT>
__global__ __launch_bounds__(64) void conv_mid(
        const float* __restrict__ in,
        const float* __restrict__ wgt,   // [Cout][CIN][3][3]
        const float* __restrict__ bias,
        const float* __restrict__ alpha,
        float* __restrict__ out,
        int Hc, int Wc) {
    int hw  = Hc * Wc;
    int pix = blockIdx.x * 64 + threadIdx.x;
    int y = pix / Wc, x = pix % Wc;
    int oc0 = blockIdx.y * NOUT;
    const float* wb = wgt + (size_t)oc0 * CIN * 9;
    float a = alpha[0];
    float acc[NOUT];
#pragma unroll
    for (int o = 0; o < NOUT; ++o) acc[o] = bias[oc0 + o];
    for (int ci = 0; ci < CIN; ++ci) {
        const float* ip = in + ci * hw;
#pragma unroll
        for (int ky = 0; ky < 3; ++ky) {
            int yy = y + ky - 1;
            bool yok = (unsigned)yy < (unsigned)Hc;
#pragma unroll
            for (int kx = 0; kx < 3; ++kx) {
                int xx = x + kx - 1;
                bool vok = yok && ((unsigned)xx < (unsigned)Wc);
                float v = ip[vok ? yy * Wc + xx : 0];
                v = vok ? v : 0.f;
#pragma unroll
                for (int o = 0; o < NOUT; ++o)
                    acc[o] += wb[(o * CIN + ci) * 9 + ky * 3 + kx] * v;
            }
        }
    }
#pragma unroll
    for (int o = 0; o < NOUT; ++o) {
        float r = acc[o];
        r = (r >= 0.f) ? r : a * r;
        out[(oc0 + o) * hw + pix] = r;
    }
}

// dual conv3 (32->1) + residual into xd ch0, split over ci-chunks of 2 (atomicAdd)
__global__ __launch_bounds__(64) void conv3d_last(const float* __restrict__ in,
        const float* __restrict__ wgt,   // [32][9]
        const float* __restrict__ bias,  // [1]
        float* __restrict__ xd) {
    int pix = blockIdx.x * 64 + threadIdx.x;   // 0..5759
    int y = pix / DD, x = pix % DD;
    int c0 = blockIdx.y * 2;
    float r = (blockIdx.y == 0) ? bias[0] : 0.f;
#pragma unroll
    for (int cc = 0; cc < 2; ++cc) {
        int ci = c0 + cc;
        const float* ip = in + ci * ADP;
#pragma unroll
        for (int ky = 0; ky < 3; ++ky) {
            int yy = y + ky - 1;
            bool yok = (unsigned)yy < (unsigned)AA;
#pragma unroll
            for (int kx = 0; kx < 3; ++kx) {
                int xx = x + kx - 1;
                bool vok = yok && ((unsigned)xx < (unsigned)DD);
                float v = ip[vok ? yy * DD + xx : 0];
                v = vok ? v : 0.f;
                r += wgt[ci * 9 + ky * 3 + kx] * v;
            }
        }
    }
    atomicAdd(xd + pix, r);
}

// primal conv3 (32->5) + residual into xp; fused: imgf for next iter (ch1),
// xp5 zero (ch2 block), final output write (ch0 block, last iter)
__global__ __launch_bounds__(64) void conv3p_last(const float* __restrict__ in,
        const float* __restrict__ wgt,   // [5][32][9]
        const float* __restrict__ bias,  // [5]
        float* __restrict__ xp, float* __restrict__ imgf,
        float* __restrict__ xp5, float* __restrict__ dout, int fin) {
    int pix = blockIdx.x * 64 + threadIdx.x;   // 0..9215
    int y = pix / WW, x = pix % WW;
    int oc = blockIdx.y;                       // 0..4
    const float* wb = wgt + (size_t)oc * 32 * 9;
    float r = bias[oc];
    for (int ci = 0; ci < 32; ++ci) {
        const float* ip = in + ci * HWP;
#pragma unroll
        for (int ky = 0; ky < 3; ++ky) {
            int yy = y + ky - 1;
            bool yok = (unsigned)yy < (unsigned)HH;
#pragma unroll
            for (int kx = 0; kx < 3; ++kx) {
                int xx = x + kx - 1;
                bool vok = yok && ((unsigned)xx < (unsigned)WW);
                float v = ip[vok ? yy * WW + xx : 0];
                v = vok ? v : 0.f;
                r += wb[ci * 9 + ky * 3 + kx] * v;
            }
        }
    }
    float nv = xp[oc * HWP + pix] + r;
    xp[oc * HWP + pix] = nv;
    if (oc == 1) imgf[x * HH + y] = nv;    // fortran flatten for next einsum1
    if (oc == 2) xp5[pix] = 0.f;           // clear evalop2 accumulator
    if (fin && oc == 0) dout[pix] = nv;    // final output
}

extern "C" void kernel_launch(void* const* d_in, const int* in_sizes, int n_in,
                              void* d_out, int out_size, void* d_ws, size_t ws_size,
                              hipStream_t stream) {
    const float* dual   = (const float*)d_in[0];
    const float* primal = (const float*)d_in[1];
    const float* g      = (const float*)d_in[2];
    const float* sysm   = (const float*)d_in[3];
    const float* norm   = (const float*)d_in[4];
    const float* dw1 = (const float*)d_in[5];
    const float* db1 = (const float*)d_in[6];
    const float* da1 = (const float*)d_in[7];
    const float* dw2 = (const float*)d_in[8];
    const float* db2 = (const float*)d_in[9];
    const float* da2 = (const float*)d_in[10];
    const float* dw3 = (const float*)d_in[11];
    const float* db3 = (const float*)d_in[12];
    const float* pw1 = (const float*)d_in[13];
    const float* pb1 = (const float*)d_in[14];
    const float* pa1 = (const float*)d_in[15];
    const float* pw2 = (const float*)d_in[16];
    const float* pb2 = (const float*)d_in[17];
    const float* pa2 = (const float*)d_in[18];
    const float* pw3 = (const float*)d_in[19];
    const float* pb3 = (const float*)d_in[20];

    unsigned short* normb = (unsigned short*)d_ws;     // MATEL bf16 [row][n]
    unsigned short* sysmb = normb + MATEL;             // MATEL bf16 [a][v][n]
    float* xd   = (float*)(sysmb + MATEL);             // 3*5760
    float* xp   = xd + 3 * ADP;                        // 6*9216
    float* imgf = xp + 6 * HWP;                        // 9216
    float* h1   = imgf + HWP;                          // 32*5760
    float* h2   = h1 + 32 * ADP;                       // 32*5760
    float* g1   = h2 + 32 * ADP;                       // 32*9216
    float* g2   = g1 + 32 * HWP;                       // 32*9216

    cvt_kernel<<<4096, 256, 0, stream>>>(norm, sysm, (ushort8*)normb, (ushort8*)sysmb, MATEL / 8);
    init_kernel<<<(5 * HWP + 255) / 256, 256, 0, stream>>>(dual, g, primal, xd, xp, imgf, xp + 5 * HWP);

    for (int k = 0; k < NITER; ++k) {
        // ---- dual half ----
        einsum1_kernel<<<ADP / 4, 256, 0, stream>>>(normb, imgf, xd + ADP);
        conv_mid<3, 1><<<dim3(ADP / 64, 32), 64, 0, stream>>>(
            xd, dw1 + k * 32 * 3 * 9, db1 + k * 32, da1 + k, h1, AA, DD);
        conv_mid<32, 1><<<dim3(ADP / 64, 32), 64, 0, stream>>>(
            h1, dw2 + k * 32 * 32 * 9, db2 + k * 32, da2 + k, h2, AA, DD);
        conv3d_last<<<dim3(ADP / 64, 16), 64, 0, stream>>>(
            h2, dw3 + k * 32 * 9, db3 + k, xd);
        // ---- primal half ----
        einsum2_kernel<<<15 * 36, 256, 0, stream>>>(sysmb, xd, xp + 5 * HWP);
        conv_mid<6, 1><<<dim3(HWP / 64, 32), 64, 0, stream>>>(
            xp, pw1 + k * 32 * 6 * 9, pb1 + k * 32, pa1 + k, g1, HH, WW);
        conv_mid<32, 1><<<dim3(HWP / 64, 32), 64, 0, stream>>>(
            g1, pw2 + k * 32 * 32 * 9, pb2 + k * 32, pa2 + k, g2, HH, WW);
        conv3p_last<<<dim3(HWP / 64, 5), 64, 0, stream>>>(
            g2, pw3 + k * 5 * 32 * 9, pb3 + k * 5, xp, imgf, xp + 5 * HWP,
            (float*)d_out, k == NITER - 1 ? 1 : 0);
    }
}

// Round 11
// 1096.056 us; speedup vs baseline: 1.3139x; 1.0336x over previous
//
#include <hip/hip_runtime.h>

#define AA 60
#define HH 96
#define WW 96
#define DD 96
#define HWP (HH * WW)   // 9216
#define ADP (AA * DD)   // 5760
#define NITER 10
#define MATEL (60 * 96 * 9216)   // 53,084,160 elements per system matrix

typedef unsigned short ushort8 __attribute__((ext_vector_type(8)));
typedef float float4v __attribute__((ext_vector_type(4)));

__device__ inline float b2f(unsigned short u) {
    return __uint_as_float(((unsigned)u) << 16);
}
__device__ inline unsigned short f2b(float f) {
    unsigned u = __float_as_uint(f);
    u += 0x7FFFu + ((u >> 16) & 1u);
    return (unsigned short)(u >> 16);
}

// ---- f32 -> bf16 conversion of both system matrices (once per call) ----
__global__ __launch_bounds__(256) void cvt_kernel(const float* __restrict__ a,
                                                  const float* __restrict__ b,
                                                  ushort8* __restrict__ da,
                                                  ushort8* __restrict__ db, int n8) {
    int stride = gridDim.x * 256;
    for (int i = blockIdx.x * 256 + threadIdx.x; i < 2 * n8; i += stride) {
        const float* src; ushort8* dst; int j;
        if (i < n8) { src = a; dst = da; j = i; }
        else        { src = b; dst = db; j = i - n8; }
        const float4v* s = reinterpret_cast<const float4v*>(src) + 2 * (size_t)j;
        float4v x = __builtin_nontemporal_load(s);
        float4v y = __builtin_nontemporal_load(s + 1);
        ushort8 o;
        o[0] = f2b(x[0]); o[1] = f2b(x[1]); o[2] = f2b(x[2]); o[3] = f2b(x[3]);
        o[4] = f2b(y[0]); o[5] = f2b(y[1]); o[6] = f2b(y[2]); o[7] = f2b(y[3]);
        dst[j] = o;
    }
}

// xd[3][5760]: ch0=dual, ch1=evalop1, ch2=g ; xp[6][9216]: ch0..4=p2d, ch5=evalop2
__global__ __launch_bounds__(256) void init_kernel(const float* __restrict__ dual,
                            const float* __restrict__ g,
                            const float* __restrict__ primal,
                            float* __restrict__ xd, float* __restrict__ xp,
                            float* __restrict__ imgf, float* __restrict__ xp5) {
    int i = blockIdx.x * 256 + threadIdx.x;
    if (i < ADP) { xd[i] = dual[i]; xd[2 * ADP + i] = g[i]; }
    if (i < 5 * HWP) xp[i] = primal[i];
    if (i < HWP) {
        imgf[(i % WW) * HH + i / WW] = primal[HWP + i];
        xp5[i] = 0.f;
    }
}

// prod[row] = dot(norm_bf16[row,:9216], imgf); one wave per ROW-PAIR
// (imgf loads shared across the two rows -> half the broadcast traffic)
__global__ __launch_bounds__(256) void einsum1_kernel(const unsigned short* __restrict__ norm,
                               const float* __restrict__ imgf,
                               float* __restrict__ out) {
    int rp   = blockIdx.x * 4 + (threadIdx.x >> 6);   // 0..2879
    int lane = threadIdx.x & 63;
    const unsigned short* r0 = norm + (size_t)(2 * rp) * HWP;
    const unsigned short* r1 = r0 + HWP;
    float s0 = 0.f, s1 = 0.f;
    for (int k = 0; k < HWP / 512; ++k) {   // 18 iters
        int n = 8 * lane + 512 * k;
        ushort8 a8 = *reinterpret_cast<const ushort8*>(r0 + n);
        ushort8 b8 = *reinterpret_cast<const ushort8*>(r1 + n);
        float4 i0 = *reinterpret_cast<const float4*>(imgf + n);
        float4 i1 = *reinterpret_cast<const float4*>(imgf + n + 4);
        s0 += b2f(a8[0]) * i0.x + b2f(a8[1]) * i0.y + b2f(a8[2]) * i0.z + b2f(a8[3]) * i0.w
            + b2f(a8[4]) * i1.x + b2f(a8[5]) * i1.y + b2f(a8[6]) * i1.z + b2f(a8[7]) * i1.w;
        s1 += b2f(b8[0]) * i0.x + b2f(b8[1]) * i0.y + b2f(b8[2]) * i0.z + b2f(b8[3]) * i0.w
            + b2f(b8[4]) * i1.x + b2f(b8[5]) * i1.y + b2f(b8[6]) * i1.z + b2f(b8[7]) * i1.w;
    }
#pragma unroll
    for (int off = 32; off > 0; off >>= 1) {
        s0 += __shfl_down(s0, off);
        s1 += __shfl_down(s1, off);
    }
    if (lane == 0) { out[2 * rp] = s0; out[2 * rp + 1] = s1; }
}

// vec[v] = sum_{a,n} sysm_bf16[a,v,n]*dual[a,n]; fortran-transposed scatter
__global__ __launch_bounds__(256) void einsum2_kernel(const unsigned short* __restrict__ sysm,
                               const float* __restrict__ xd,
                               float* __restrict__ xp5) {
    __shared__ float sd[4 * DD];
    int t  = threadIdx.x;
    int a0 = (blockIdx.x % 15) * 4;
    int v  = (blockIdx.x / 15) * 256 + t;
    for (int j = t; j < 4 * DD; j += 256) sd[j] = xd[a0 * DD + j];
    __syncthreads();
    float s = 0.f;
    for (int ai = 0; ai < 4; ++ai) {
        const unsigned short* row = sysm + ((size_t)(a0 + ai) * HWP + v) * DD;
        const float* dl = sd + ai * DD;
#pragma unroll
        for (int jj = 0; jj < DD / 8; ++jj) {
            ushort8 m8 = *reinterpret_cast<const ushort8*>(row + 8 * jj);
            s += b2f(m8[0]) * dl[8 * jj]     + b2f(m8[1]) * dl[8 * jj + 1]
               + b2f(m8[2]) * dl[8 * jj + 2] + b2f(m8[3]) * dl[8 * jj + 3]
               + b2f(m8[4]) * dl[8 * jj + 4] + b2f(m8[5]) * dl[8 * jj + 5]
               + b2f(m8[6]) * dl[8 * jj + 6] + b2f(m8[7]) * dl[8 * jj + 7];
        }
    }
    atomicAdd(xp5 + (v % HH) * WW + (v / HH), s);
}

// 3x3 conv pad=1, PReLU. Grid: (hw/64, Cout/NOUT), block 64.
template <int CIN, int NOUT>
__global__ __launch_bounds__(64) void conv_mid(
        const float* __restrict__ in,
        const float* __restrict__ wgt,   // [Cout][CIN][3][3]
        const float* __restrict__ bias,
        const float* __restrict__ alpha,
        float* __restrict__ out,
        int Hc, int Wc) {
    int hw  = Hc * Wc;
    int pix = blockIdx.x * 64 + threadIdx.x;
    int y = pix / Wc, x = pix % Wc;
    int oc0 = blockIdx.y * NOUT;
    const float* wb = wgt + (size_t)oc0 * CIN * 9;
    float a = alpha[0];
    float acc[NOUT];
#pragma unroll
    for (int o = 0; o < NOUT; ++o) acc[o] = bias[oc0 + o];
    for (int ci = 0; ci < CIN; ++ci) {
        const float* ip = in + ci * hw;
#pragma unroll
        for (int ky = 0; ky < 3; ++ky) {
            int yy = y + ky - 1;
            bool yok = (unsigned)yy < (unsigned)Hc;
#pragma unroll
            for (int kx = 0; kx < 3; ++kx) {
                int xx = x + kx - 1;
                bool vok = yok && ((unsigned)xx < (unsigned)Wc);
                float v = ip[vok ? yy * Wc + xx : 0];
                v = vok ? v : 0.f;
#pragma unroll
                for (int o = 0; o < NOUT; ++o)
                    acc[o] += wb[(o * CIN + ci) * 9 + ky * 3 + kx] * v;
            }
        }
    }
#pragma unroll
    for (int o = 0; o < NOUT; ++o) {
        float r = acc[o];
        r = (r >= 0.f) ? r : a * r;
        out[(oc0 + o) * hw + pix] = r;
    }
}

// dual conv3 (32->1) + residual into xd ch0, split over ci-chunks of 4 (atomicAdd)
__global__ __launch_bounds__(64) void conv3d_last(const float* __restrict__ in,
        const float* __restrict__ wgt,   // [32][9]
        const float* __restrict__ bias,  // [1]
        float* __restrict__ xd) {
    int pix = blockIdx.x * 64 + threadIdx.x;   // 0..5759
    int y = pix / DD, x = pix % DD;
    int c0 = blockIdx.y * 4;
    float r = (blockIdx.y == 0) ? bias[0] : 0.f;
    for (int ci = c0; ci < c0 + 4; ++ci) {
        const float* ip = in + ci * ADP;
#pragma unroll
        for (int ky = 0; ky < 3; ++ky) {
            int yy = y + ky - 1;
            bool yok = (unsigned)yy < (unsigned)AA;
#pragma unroll
            for (int kx = 0; kx < 3; ++kx) {
                int xx = x + kx - 1;
                bool vok = yok && ((unsigned)xx < (unsigned)DD);
                float v = ip[vok ? yy * DD + xx : 0];
                v = vok ? v : 0.f;
                r += wgt[ci * 9 + ky * 3 + kx] * v;
            }
        }
    }
    atomicAdd(xd + pix, r);
}

// primal conv3 (32->5) + residual into xp; fused: imgf for next iter (ch1),
// xp5 zero (ch2 block), final output write (ch0 block, last iter)
__global__ __launch_bounds__(64) void conv3p_last(const float* __restrict__ in,
        const float* __restrict__ wgt,   // [5][32][9]
        const float* __restrict__ bias,  // [5]
        float* __restrict__ xp, float* __restrict__ imgf,
        float* __restrict__ xp5, float* __restrict__ dout, int fin) {
    int pix = blockIdx.x * 64 + threadIdx.x;   // 0..9215
    int y = pix / WW, x = pix % WW;
    int oc = blockIdx.y;                       // 0..4
    const float* wb = wgt + (size_t)oc * 32 * 9;
    float r = bias[oc];
    for (int ci = 0; ci < 32; ++ci) {
        const float* ip = in + ci * HWP;
#pragma unroll
        for (int ky = 0; ky < 3; ++ky) {
            int yy = y + ky - 1;
            bool yok = (unsigned)yy < (unsigned)HH;
#pragma unroll
            for (int kx = 0; kx < 3; ++kx) {
                int xx = x + kx - 1;
                bool vok = yok && ((unsigned)xx < (unsigned)WW);
                float v = ip[vok ? yy * WW + xx : 0];
                v = vok ? v : 0.f;
                r += wb[ci * 9 + ky * 3 + kx] * v;
            }
        }
    }
    float nv = xp[oc * HWP + pix] + r;
    xp[oc * HWP + pix] = nv;
    if (oc == 1) imgf[x * HH + y] = nv;    // fortran flatten for next einsum1
    if (oc == 2) xp5[pix] = 0.f;           // clear evalop2 accumulator
    if (fin && oc == 0) dout[pix] = nv;    // final output
}

extern "C" void kernel_launch(void* const* d_in, const int* in_sizes, int n_in,
                              void* d_out, int out_size, void* d_ws, size_t ws_size,
                              hipStream_t stream) {
    const float* dual   = (const float*)d_in[0];
    const float* primal = (const float*)d_in[1];
    const float* g      = (const float*)d_in[2];
    const float* sysm   = (const float*)d_in[3];
    const float* norm   = (const float*)d_in[4];
    const float* dw1 = (const float*)d_in[5];
    const float* db1 = (const float*)d_in[6];
    const float* da1 = (const float*)d_in[7];
    const float* dw2 = (const float*)d_in[8];
    const float* db2 = (const float*)d_in[9];
    const float* da2 = (const float*)d_in[10];
    const float* dw3 = (const float*)d_in[11];
    const float* db3 = (const float*)d_in[12];
    const float* pw1 = (const float*)d_in[13];
    const float* pb1 = (const float*)d_in[14];
    const float* pa1 = (const float*)d_in[15];
    const float* pw2 = (const float*)d_in[16];
    const float* pb2 = (const float*)d_in[17];
    const float* pa2 = (const float*)d_in[18];
    const float* pw3 = (const float*)d_in[19];
    const float* pb3 = (const float*)d_in[20];

    unsigned short* normb = (unsigned short*)d_ws;     // MATEL bf16 [row][n]
    unsigned short* sysmb = normb + MATEL;             // MATEL bf16 [a][v][n]
    float* xd   = (float*)(sysmb + MATEL);             // 3*5760
    float* xp   = xd + 3 * ADP;                        // 6*9216
    float* imgf = xp + 6 * HWP;                        // 9216
    float* h1   = imgf + HWP;                          // 32*5760
    float* h2   = h1 + 32 * ADP;                       // 32*5760
    float* g1   = h2 + 32 * ADP;                       // 32*9216
    float* g2   = g1 + 32 * HWP;                       // 32*9216

    cvt_kernel<<<4096, 256, 0, stream>>>(norm, sysm, (ushort8*)normb, (ushort8*)sysmb, MATEL / 8);
    init_kernel<<<(5 * HWP + 255) / 256, 256, 0, stream>>>(dual, g, primal, xd, xp, imgf, xp + 5 * HWP);

    for (int k = 0; k < NITER; ++k) {
        // ---- dual half ----
        einsum1_kernel<<<ADP / 8, 256, 0, stream>>>(normb, imgf, xd + ADP);
        conv_mid<3, 2><<<dim3(ADP / 64, 16), 64, 0, stream>>>(
            xd, dw1 + k * 32 * 3 * 9, db1 + k * 32, da1 + k, h1, AA, DD);
        conv_mid<32, 2><<<dim3(ADP / 64, 16), 64, 0, stream>>>(
            h1, dw2 + k * 32 * 32 * 9, db2 + k * 32, da2 + k, h2, AA, DD);
        conv3d_last<<<dim3(ADP / 64, 8), 64, 0, stream>>>(
            h2, dw3 + k * 32 * 9, db3 + k, xd);
        // ---- primal half ----
        einsum2_kernel<<<15 * 36, 256, 0, stream>>>(sysmb, xd, xp + 5 * HWP);
        conv_mid<6, 2><<<dim3(HWP / 64, 16), 64, 0, stream>>>(
            xp, pw1 + k * 32 * 6 * 9, pb1 + k * 32, pa1 + k, g1, HH, WW);
        conv_mid<32, 2><<<dim3(HWP / 64, 16), 64, 0, stream>>>(
            g1, pw2 + k * 32 * 32 * 9, pb2 + k * 32, pa2 + k, g2, HH, WW);
        conv3p_last<<<dim3(HWP / 64, 5), 64, 0, stream>>>(
            g2, pw3 + k * 5 * 32 * 9, pb3 + k * 5, xp, imgf, xp + 5 * HWP,
            (float*)d_out, k == NITER - 1 ? 1 : 0);
    }
}